// Round 1
// baseline (356.267 us; speedup 1.0000x reference)
//
#include <hip/hip_runtime.h>

#define D 256
#define S 2048
#define B 8
#define TT 16   // t-tile for bulk kernel
#define DSQ (D * D)   // 65536

// ws layout (floats):
// [0, 2048)          total[b][d]
// [2048, 4096)       Tb[b][o]  (= bias + total @ W3 / (S-5))
// [4096, 4096+5*DSQ) C[5][i][o]

__global__ void k_total(const float* __restrict__ x, float* __restrict__ total) {
    int b = blockIdx.x;
    int chunk = blockIdx.y;            // 16 chunks of 128 rows each
    int d = threadIdx.x;
    const float* xb = x + ((size_t)b * S + (size_t)chunk * 128) * D + d;
    float s = 0.f;
    #pragma unroll 4
    for (int i = 0; i < 128; ++i) s += xb[(size_t)i * D];
    atomicAdd(&total[b * D + d], s);
}

__global__ void k_buildC(const float* __restrict__ basis, const float* __restrict__ comp,
                         const float* __restrict__ root, float* __restrict__ C) {
    int i = blockIdx.x, o = threadIdx.x;
    int idx = i * D + o;
    float b0 = basis[idx];
    float b1 = basis[DSQ + idx];
    float rt = root[idx];
    float W0 = comp[0] * b0 + comp[1] * b1;
    float W1 = comp[2] * b0 + comp[3] * b1;
    float W2 = comp[4] * b0 + comp[5] * b1;
    float W3 = comp[6] * b0 + comp[7] * b1;
    const float inv3 = 1.0f / (float)(S - 5);
    float w3s = inv3 * W3;
    C[0 * DSQ + idx] = 0.5f * W2 - w3s;            // j = -1
    C[1 * DSQ + idx] = 0.5f * W1 + rt - w3s;       // j = 0
    C[2 * DSQ + idx] = W0 - w3s;                   // j = +1
    C[3 * DSQ + idx] = 0.5f * W1 - w3s;            // j = +2
    C[4 * DSQ + idx] = 0.5f * W2 - w3s;            // j = +3
}

__global__ void k_Tb(const float* __restrict__ basis, const float* __restrict__ comp,
                     const float* __restrict__ bias, const float* __restrict__ total,
                     float* __restrict__ Tb) {
    int b = blockIdx.x, o = threadIdx.x;
    float c30 = comp[6], c31 = comp[7];
    const float inv3 = 1.0f / (float)(S - 5);
    float acc = 0.f;
    for (int i = 0; i < D; ++i) {
        float t = total[b * D + i];
        acc += t * (c30 * basis[i * D + o] + c31 * basis[DSQ + i * D + o]);
    }
    Tb[b * D + o] = bias[o] + inv3 * acc;
}

__global__ __launch_bounds__(256) void k_bulk(const float* __restrict__ x,
                                              const float* __restrict__ C,
                                              const float* __restrict__ Tb,
                                              float* __restrict__ out) {
    __shared__ float xs[TT + 4][D];   // rows t0-1 .. t0+18
    int tile = blockIdx.x, b = blockIdx.y;
    int t0 = 1 + tile * TT;
    int tid = threadIdx.x;
    const float* xb = x + (size_t)b * S * D;

    #pragma unroll
    for (int i = 0; i < TT + 4; ++i) {
        int r = t0 - 1 + i;
        if (r > S - 1) r = S - 1;     // clamp (values unused when masked)
        xs[i][tid] = xb[(size_t)r * D + tid];
    }
    __syncthreads();

    float acc[TT];
    #pragma unroll
    for (int lt = 0; lt < TT; ++lt) acc[lt] = 0.f;

    for (int ji = 0; ji < 5; ++ji) {          // j = ji - 1; x row = t + ji - 1 -> xs[lt + ji]
        const float* Cj = C + ji * DSQ + tid; // this thread's output column
        #pragma unroll 1
        for (int k = 0; k < D; k += 4) {
            float w0 = Cj[(k + 0) * D];
            float w1 = Cj[(k + 1) * D];
            float w2 = Cj[(k + 2) * D];
            float w3 = Cj[(k + 3) * D];
            #pragma unroll
            for (int lt = 0; lt < TT; ++lt) {
                float4 xv = *(const float4*)&xs[lt + ji][k];   // wave-uniform broadcast
                acc[lt] += xv.x * w0 + xv.y * w1 + xv.z * w2 + xv.w * w3;
            }
        }
    }

    float tb = Tb[b * D + tid];
    #pragma unroll
    for (int lt = 0; lt < TT; ++lt) {
        int t = t0 + lt;
        if (t <= S - 4) out[((size_t)b * S + t) * D + tid] = acc[lt] + tb;
    }
}

__global__ void k_boundary(const float* __restrict__ x, const float* __restrict__ basis,
                           const float* __restrict__ comp, const float* __restrict__ root,
                           const float* __restrict__ bias, const float* __restrict__ total,
                           float* __restrict__ out) {
    const int tlist[4] = {0, S - 3, S - 2, S - 1};
    int t = tlist[blockIdx.x];
    int b = blockIdx.y;
    int i = threadIdx.x;     // channel index for gather phase
    __shared__ float z0[D], z1[D], xr[D];
    const float* xb = x + (size_t)b * S * D;

    float x_t = xb[(size_t)t * D + i];
    // r=0: source t+1
    float v0 = (t + 1 < S) ? xb[(size_t)(t + 1) * D + i] : 0.f;
    // r=1: sources {t, t+2}
    float d1 = 1.f + ((t + 2 < S) ? 1.f : 0.f);
    float v1 = (x_t + ((t + 2 < S) ? xb[(size_t)(t + 2) * D + i] : 0.f)) / d1;
    // r=2: sources {t-1, t+3}
    float s2 = ((t - 1 >= 0) ? xb[(size_t)(t - 1) * D + i] : 0.f)
             + ((t + 3 < S) ? xb[(size_t)(t + 3) * D + i] : 0.f);
    int d2i = ((t - 1 >= 0) ? 1 : 0) + ((t + 3 < S) ? 1 : 0);
    float v2 = (d2i > 0) ? s2 / (float)d2i : 0.f;
    // r=3: everything outside window [t-1, t+3]
    float wsum = 0.f;
    for (int s = t - 1; s <= t + 3; ++s)
        if (s >= 0 && s < S) wsum += xb[(size_t)s * D + i];
    int d3i = ((t - 1 > 0) ? (t - 1) : 0) + ((S - 4 - t > 0) ? (S - 4 - t) : 0);
    float v3 = (d3i > 0) ? (total[b * D + i] - wsum) / (float)d3i : 0.f;

    // z_bases[i] = sum_r comp[r, base] * v_r[i]
    z0[i] = comp[0] * v0 + comp[2] * v1 + comp[4] * v2 + comp[6] * v3;
    z1[i] = comp[1] * v0 + comp[3] * v1 + comp[5] * v2 + comp[7] * v3;
    xr[i] = x_t;
    __syncthreads();

    int o = threadIdx.x;     // output column for GEMV phase
    float acc = 0.f;
    for (int k = 0; k < D; ++k) {
        acc += z0[k] * basis[k * D + o]
             + z1[k] * basis[DSQ + k * D + o]
             + xr[k] * root[k * D + o];
    }
    out[((size_t)b * S + t) * D + o] = acc + bias[o];
}

extern "C" void kernel_launch(void* const* d_in, const int* in_sizes, int n_in,
                              void* d_out, int out_size, void* d_ws, size_t ws_size,
                              hipStream_t stream) {
    const float* x     = (const float*)d_in[0];
    const float* comp  = (const float*)d_in[1];
    const float* basis = (const float*)d_in[2];
    const float* root  = (const float*)d_in[3];
    const float* bias  = (const float*)d_in[4];
    float* out = (float*)d_out;

    float* total = (float*)d_ws;
    float* Tb    = total + B * D;        // 2048
    float* C     = Tb + B * D;           // 2048

    hipMemsetAsync(total, 0, B * D * sizeof(float), stream);
    k_total   <<<dim3(B, 16), 256, 0, stream>>>(x, total);
    k_buildC  <<<256,         256, 0, stream>>>(basis, comp, root, C);
    k_Tb      <<<B,           256, 0, stream>>>(basis, comp, bias, total, Tb);
    k_bulk    <<<dim3(S / TT, B), 256, 0, stream>>>(x, C, Tb, out);
    k_boundary<<<dim3(4, B),  256, 0, stream>>>(x, basis, comp, root, bias, total, out);
}

// Round 2
// 133.826 us; speedup vs baseline: 2.6622x; 2.6622x over previous
//
#include <hip/hip_runtime.h>

#define D 256
#define S 2048
#define B 8
#define DSQ (D * D)   // 65536
#define INV3 (1.0f / 2043.0f)   // 1/(S-5)

typedef __bf16 bf16x8 __attribute__((ext_vector_type(8)));
typedef float f32x4 __attribute__((ext_vector_type(4)));

__device__ __forceinline__ unsigned short f2bf(float f) {
    union { float f; unsigned int u; } v; v.f = f;
    unsigned int u = v.u;
    u += 0x7fffu + ((u >> 16) & 1u);   // RTNE
    return (unsigned short)(u >> 16);
}

__device__ __forceinline__ void gl2lds16(const void* g, void* l) {
    __builtin_amdgcn_global_load_lds(
        (const __attribute__((address_space(1))) void*)g,
        (__attribute__((address_space(3))) void*)l, 16, 0, 0);
}

// ---------------- small kernels ----------------

__global__ void k_total(const float* __restrict__ x, float* __restrict__ total) {
    int b = blockIdx.x, chunk = blockIdx.y, d = threadIdx.x;
    const float* xb = x + ((size_t)b * S + (size_t)chunk * 128) * D + d;
    float s = 0.f;
    #pragma unroll 4
    for (int i = 0; i < 128; ++i) s += xb[(size_t)i * D];
    atomicAdd(&total[b * D + d], s);
}

__global__ void k_xh(const float* __restrict__ x, unsigned short* __restrict__ xh) {
    int i = blockIdx.x * 256 + threadIdx.x;      // one float4 per thread
    float4 v = ((const float4*)x)[i];
    ushort4 o;
    o.x = f2bf(v.x); o.y = f2bf(v.y); o.z = f2bf(v.z); o.w = f2bf(v.w);
    ((ushort4*)(xh + D))[i] = o;                 // +D: skip 1 pad row in front
}

// Cbs[step=ji*8+kc][n=256][kk=32] bf16, pre-chunked for flat 8KB B-tile staging
__global__ void k_buildCbs(const float* __restrict__ basis, const float* __restrict__ comp,
                           const float* __restrict__ root, unsigned short* __restrict__ Cbs) {
    int step = blockIdx.x;          // 0..39
    int ji = step >> 3, kc = step & 7;
    int n = threadIdx.x;            // output col o
    float a0 = (ji == 2) ? 1.f : 0.f;
    float a1 = (ji == 1 || ji == 3) ? 0.5f : 0.f;
    float a2 = (ji == 0 || ji == 4) ? 0.5f : 0.f;
    float ar = (ji == 1) ? 1.f : 0.f;
    float cb0 = a0 * comp[0] + a1 * comp[2] + a2 * comp[4] - INV3 * comp[6];
    float cb1 = a0 * comp[1] + a1 * comp[3] + a2 * comp[5] - INV3 * comp[7];
    unsigned short buf[32];
    #pragma unroll
    for (int kk = 0; kk < 32; ++kk) {
        int i = kc * 32 + kk;
        float v = cb0 * basis[i * D + n] + cb1 * basis[DSQ + i * D + n] + ar * root[i * D + n];
        buf[kk] = f2bf(v);
    }
    uint4* dst = (uint4*)(Cbs + ((size_t)step * 256 + n) * 32);
    uint4* src = (uint4*)buf;
    #pragma unroll
    for (int j = 0; j < 4; ++j) dst[j] = src[j];
}

// bias -> Tb rows and boundary out rows
__global__ void k_init(const float* __restrict__ bias, float* __restrict__ Tb,
                       float* __restrict__ out) {
    int o = threadIdx.x, blk = blockIdx.x;   // 0..39
    float bv = bias[o];
    if (blk < 8) {
        Tb[blk * D + o] = bv;
    } else {
        int r = blk - 8;                     // 0..31
        int b = r >> 2;
        const int tl[4] = {0, S - 3, S - 2, S - 1};
        int t = tl[r & 3];
        out[(((size_t)b * S + t) << 8) + o] = bv;
    }
}

__global__ void k_Tb2(const float* __restrict__ basis, const float* __restrict__ comp,
                      const float* __restrict__ total, float* __restrict__ Tb) {
    int b = blockIdx.x, kc = blockIdx.y, o = threadIdx.x;
    float c30 = comp[6], c31 = comp[7];
    float acc = 0.f;
    #pragma unroll 8
    for (int kk = 0; kk < 32; ++kk) {
        int i = kc * 32 + kk;
        acc += total[b * D + i] * (c30 * basis[i * D + o] + c31 * basis[DSQ + i * D + o]);
    }
    atomicAdd(&Tb[b * D + o], acc * INV3);
}

__global__ void k_boundary2(const float* __restrict__ x, const float* __restrict__ basis,
                            const float* __restrict__ root, const float* __restrict__ comp,
                            const float* __restrict__ total, float* __restrict__ out) {
    const int tl[4] = {0, S - 3, S - 2, S - 1};
    int t = tl[blockIdx.x], b = blockIdx.y, kc = blockIdx.z;
    __shared__ float z0[32], z1[32], xr[32];
    const float* xb = x + (size_t)b * S * D;
    int tid = threadIdx.x;
    if (tid < 32) {
        int i = kc * 32 + tid;
        float x_t = xb[(size_t)t * D + i];
        float v0 = (t + 1 < S) ? xb[(size_t)(t + 1) * D + i] : 0.f;
        float d1 = 1.f + ((t + 2 < S) ? 1.f : 0.f);
        float v1 = (x_t + ((t + 2 < S) ? xb[(size_t)(t + 2) * D + i] : 0.f)) / d1;
        float s2 = ((t - 1 >= 0) ? xb[(size_t)(t - 1) * D + i] : 0.f)
                 + ((t + 3 < S) ? xb[(size_t)(t + 3) * D + i] : 0.f);
        int d2i = ((t - 1 >= 0) ? 1 : 0) + ((t + 3 < S) ? 1 : 0);
        float v2 = d2i ? s2 / (float)d2i : 0.f;
        float wsum = 0.f;
        for (int s = t - 1; s <= t + 3; ++s)
            if (s >= 0 && s < S) wsum += xb[(size_t)s * D + i];
        int d3i = ((t - 1 > 0) ? (t - 1) : 0) + ((S - 4 - t > 0) ? (S - 4 - t) : 0);
        float v3 = d3i ? (total[b * D + i] - wsum) / (float)d3i : 0.f;
        z0[tid] = comp[0] * v0 + comp[2] * v1 + comp[4] * v2 + comp[6] * v3;
        z1[tid] = comp[1] * v0 + comp[3] * v1 + comp[5] * v2 + comp[7] * v3;
        xr[tid] = x_t;
    }
    __syncthreads();
    int o = tid;
    float acc = 0.f;
    #pragma unroll 8
    for (int kk = 0; kk < 32; ++kk) {
        int k = kc * 32 + kk;
        acc += z0[kk] * basis[k * D + o] + z1[kk] * basis[DSQ + k * D + o]
             + xr[kk] * root[k * D + o];
    }
    atomicAdd(&out[(((size_t)b * S + t) << 8) + o], acc);
}

// ---------------- MFMA bulk GEMM ----------------
// Block = 64(m) x 128(n), 128 threads = 2 waves (each wave 64x64 via 4x4 of 16x16x32).
// A[m][ji*256+k] = x[t0+m+ji-1][k] read from a 68-row x tile staged ONCE per block.
// B = Cbs chunk, double-buffered 8KB tiles. XOR chunk swizzles keep LDS reads <=2-way.

__global__ __launch_bounds__(128) void k_bulk_mfma(
        const unsigned short* __restrict__ xh,   // padded rows: [1 + B*S + 3]
        const unsigned short* __restrict__ Cbs,  // [40][256][32]
        const float* __restrict__ Tb,
        float* __restrict__ out) {
    __shared__ __align__(16) unsigned short xs[68 * 256];     // 34816 B
    __shared__ __align__(16) unsigned short Bs[2][128 * 32];  // 2 x 8192 B
    const int tid  = threadIdx.x;
    const int lane = tid & 63;
    const int w    = tid >> 6;          // wave id -> n offset w*64
    const int mblk = blockIdx.x;        // 0..255
    const int nblk = blockIdx.y;        // 0..1
    const int b  = mblk >> 5;
    const int t0 = (mblk & 31) << 6;
    const size_t rowbase = (size_t)b * S + t0;   // padded row of x[b][t0-1]

    // stage x tile: 68 rows x 512B, chunk-swizzled: LDS[r][c16] <- global chunk (c16&24)|((c16^r)&7)
    #pragma unroll
    for (int q = 0; q < 17; ++q) {
        int F = (q * 128 + tid) * 16;            // flat LDS byte
        int r = F >> 9;
        int c16 = (F >> 4) & 31;
        int gc = (c16 & 24) | ((c16 ^ r) & 7);
        gl2lds16((const char*)xh + ((rowbase + r) << 9) + (gc << 4), (char*)xs + F);
    }
    // stage B step 0
    {
        const size_t gb = ((size_t)0 * 256 + nblk * 128) << 6;
        #pragma unroll
        for (int q = 0; q < 4; ++q) {
            int i = q * 128 + tid;
            int rn = i >> 2, c = i & 3;
            int gc = c ^ (rn & 3) ^ ((rn >> 2) & 3);
            gl2lds16((const char*)Cbs + gb + ((size_t)rn << 6) + (gc << 4),
                     (char*)Bs[0] + i * 16);
        }
    }
    __syncthreads();

    f32x4 acc[4][4] = {};
    const int rlo = lane & 15, q4 = lane >> 4;

    for (int step = 0; step < 40; ++step) {
        int cur = step & 1;
        if (step + 1 < 40) {   // prefetch next B tile
            const size_t gb = (((size_t)(step + 1)) * 256 + nblk * 128) << 6;
            #pragma unroll
            for (int q = 0; q < 4; ++q) {
                int i = q * 128 + tid;
                int rn = i >> 2, c = i & 3;
                int gc = c ^ (rn & 3) ^ ((rn >> 2) & 3);
                gl2lds16((const char*)Cbs + gb + ((size_t)rn << 6) + (gc << 4),
                         (char*)Bs[cur ^ 1] + i * 16);
            }
        }
        int ji = step >> 3, kc = step & 7;
        bf16x8 a[4], bb[4];
        #pragma unroll
        for (int mt = 0; mt < 4; ++mt) {
            int r = mt * 16 + rlo + ji;          // xs row (m + ji), 0..67
            int cc = kc * 4 + q4;
            int c16 = (cc & 24) | ((cc ^ r) & 7);
            a[mt] = *(const bf16x8*)((const char*)xs + (r << 9) + (c16 << 4));
        }
        #pragma unroll
        for (int nt = 0; nt < 4; ++nt) {
            int n = w * 64 + nt * 16 + rlo;      // 0..127
            int c = q4 ^ (n & 3) ^ ((n >> 2) & 3);
            bb[nt] = *(const bf16x8*)((const char*)Bs[cur] + (n << 6) + (c << 4));
        }
        #pragma unroll
        for (int mt = 0; mt < 4; ++mt)
            #pragma unroll
            for (int nt = 0; nt < 4; ++nt)
                acc[mt][nt] = __builtin_amdgcn_mfma_f32_16x16x32_bf16(a[mt], bb[nt], acc[mt][nt], 0, 0, 0);
        __syncthreads();
    }

    // epilogue: C/D layout col=lane&15, row=(lane>>4)*4+i
    const int col = lane & 15, rq = (lane >> 4) << 2;
    #pragma unroll
    for (int nt = 0; nt < 4; ++nt) {
        int n = nblk * 128 + w * 64 + nt * 16 + col;
        float tb = Tb[b * D + n];
        #pragma unroll
        for (int mt = 0; mt < 4; ++mt) {
            #pragma unroll
            for (int i = 0; i < 4; ++i) {
                int t = t0 + mt * 16 + rq + i;
                if (t >= 1 && t <= S - 4)
                    out[(((size_t)b * S + t) << 8) + n] = acc[mt][nt][i] + tb;
            }
        }
    }
}

// ---------------- launch ----------------

extern "C" void kernel_launch(void* const* d_in, const int* in_sizes, int n_in,
                              void* d_out, int out_size, void* d_ws, size_t ws_size,
                              hipStream_t stream) {
    const float* x     = (const float*)d_in[0];
    const float* comp  = (const float*)d_in[1];
    const float* basis = (const float*)d_in[2];
    const float* root  = (const float*)d_in[3];
    const float* bias  = (const float*)d_in[4];
    float* out = (float*)d_out;

    char* ws = (char*)d_ws;
    float* total          = (float*)(ws);                    // 8192 B
    float* Tb             = (float*)(ws + 8192);             // 8192 B
    unsigned short* Cbs   = (unsigned short*)(ws + 16384);   // 655360 B
    unsigned short* xh    = (unsigned short*)(ws + 671744);  // 16388 rows * 512 B

    hipMemsetAsync(total, 0, B * D * sizeof(float), stream);
    k_total    <<<dim3(B, 16), 256, 0, stream>>>(x, total);
    k_xh       <<<4096,        256, 0, stream>>>(x, xh);
    k_buildCbs <<<40,          256, 0, stream>>>(basis, comp, root, Cbs);
    k_init     <<<40,          256, 0, stream>>>(bias, Tb, out);
    k_Tb2      <<<dim3(B, 8),  256, 0, stream>>>(basis, comp, total, Tb);
    k_bulk_mfma<<<dim3(256, 2), 128, 0, stream>>>(xh, Cbs, Tb, out);
    k_boundary2<<<dim3(4, B, 8), 256, 0, stream>>>(x, basis, root, comp, total, out);
}

// Round 3
// 127.647 us; speedup vs baseline: 2.7910x; 1.0484x over previous
//
#include <hip/hip_runtime.h>

#define D 256
#define S 2048
#define B 8
#define DSQ (D * D)   // 65536
#define INV3 (1.0f / 2043.0f)   // 1/(S-5)

typedef __bf16 bf16x8 __attribute__((ext_vector_type(8)));
typedef float f32x4 __attribute__((ext_vector_type(4)));

__device__ __forceinline__ unsigned short f2bf(float f) {
    union { float f; unsigned int u; } v; v.f = f;
    unsigned int u = v.u;
    u += 0x7fffu + ((u >> 16) & 1u);   // RTNE
    return (unsigned short)(u >> 16);
}

__device__ __forceinline__ void gl2lds16(const void* g, void* l) {
    __builtin_amdgcn_global_load_lds(
        (const __attribute__((address_space(1))) void*)g,
        (__attribute__((address_space(3))) void*)l, 16, 0, 0);
}

// s_waitcnt imm: vmcnt=imm[3:0]|imm[15:14]<<4, expcnt=imm[6:4], lgkmcnt=imm[11:8]
#define WAIT_VM4()  { __builtin_amdgcn_s_waitcnt(0xF74); asm volatile("" ::: "memory"); }
#define WAIT_VM8()  { __builtin_amdgcn_s_waitcnt(0xF78); asm volatile("" ::: "memory"); }
#define BARRIER()   { asm volatile("" ::: "memory"); __builtin_amdgcn_s_barrier(); asm volatile("" ::: "memory"); }

// ---------------- K1: bf16 cast + per-batch channel totals ----------------
// grid (B, 64) x 256 thr; block handles 32 rows; thread: 4 channels x 8 rows.
__global__ __launch_bounds__(256) void k_prep(const float* __restrict__ x,
                                              unsigned short* __restrict__ xh,
                                              float* __restrict__ total) {
    int b = blockIdx.x, chunk = blockIdx.y;
    int tid = threadIdx.x;
    int rg = tid >> 6;               // 0..3 row-group
    int c4 = (tid & 63) << 2;        // channel*4
    __shared__ float part[4][D];
    int row0 = chunk * 32 + rg * 8;
    const float4* xb = (const float4*)(x + ((size_t)b * S + row0) * D + c4);
    ushort4* dst = (ushort4*)(xh + ((size_t)(1 + b * S + row0)) * D + c4);
    float4 s = {0.f, 0.f, 0.f, 0.f};
    #pragma unroll
    for (int i = 0; i < 8; ++i) {
        float4 v = xb[(size_t)i * 64];
        ushort4 o;
        o.x = f2bf(v.x); o.y = f2bf(v.y); o.z = f2bf(v.z); o.w = f2bf(v.w);
        dst[(size_t)i * 64] = o;
        s.x += v.x; s.y += v.y; s.z += v.z; s.w += v.w;
    }
    *(float4*)&part[rg][c4] = s;
    __syncthreads();
    float t = part[0][tid] + part[1][tid] + part[2][tid] + part[3][tid];
    atomicAdd(&total[b * D + tid], t);
}

// ---------------- K2: Cbs build + Tb + boundary rows (one dispatch) -------
// blocks [0,160): Cbs; [160,192): Tb; [192,224): boundary rows.
__global__ __launch_bounds__(256) void k_weights(
        const float* __restrict__ basis, const float* __restrict__ comp,
        const float* __restrict__ root, const float* __restrict__ bias,
        const float* __restrict__ total, const float* __restrict__ x,
        unsigned short* __restrict__ Cbs, float* __restrict__ Tb,
        float* __restrict__ out) {
    int blk = blockIdx.x;
    int tid = threadIdx.x;

    if (blk < 160) {                         // ---- Cbs[step][n][32] bf16
        int step = blk >> 2, q = blk & 3;    // q: quarter of the 32-k chunk
        int ji = step >> 3, kc = step & 7;
        int n = tid;
        float a0 = (ji == 2) ? 1.f : 0.f;
        float a1 = (ji == 1 || ji == 3) ? 0.5f : 0.f;
        float a2 = (ji == 0 || ji == 4) ? 0.5f : 0.f;
        float ar = (ji == 1) ? 1.f : 0.f;
        float cb0 = a0 * comp[0] + a1 * comp[2] + a2 * comp[4] - INV3 * comp[6];
        float cb1 = a0 * comp[1] + a1 * comp[3] + a2 * comp[5] - INV3 * comp[7];
        unsigned short buf[8];
        #pragma unroll
        for (int kk = 0; kk < 8; ++kk) {
            int i = kc * 32 + q * 8 + kk;
            float v = cb0 * basis[i * D + n] + cb1 * basis[DSQ + i * D + n]
                    + ar * root[i * D + n];
            buf[kk] = f2bf(v);
        }
        *(uint4*)(Cbs + ((size_t)step * 256 + n) * 32 + q * 8) = *(uint4*)buf;
    } else if (blk < 192) {                  // ---- Tb[b][o] = bias + total@W3*INV3
        int r = blk - 160;
        int b = r >> 2, kq = r & 3;
        int o = tid;
        float c30 = comp[6], c31 = comp[7];
        float acc = 0.f;
        #pragma unroll 8
        for (int kk = 0; kk < 64; ++kk) {
            int k = kq * 64 + kk;
            acc += total[b * D + k] * (c30 * basis[k * D + o] + c31 * basis[DSQ + k * D + o]);
        }
        atomicAdd(&Tb[b * D + o], acc * INV3 + (kq == 0 ? bias[o] : 0.f));
    } else {                                 // ---- boundary rows t in {0,S-3,S-2,S-1}
        int r = blk - 192;
        const int tl[4] = {0, S - 3, S - 2, S - 1};
        int t = tl[r & 3], b = r >> 2;
        __shared__ float z0[D], z1[D], xr[D];
        const float* xb = x + (size_t)b * S * D;
        int i = tid;
        float x_t = xb[(size_t)t * D + i];
        float v0 = (t + 1 < S) ? xb[(size_t)(t + 1) * D + i] : 0.f;
        float d1 = 1.f + ((t + 2 < S) ? 1.f : 0.f);
        float v1 = (x_t + ((t + 2 < S) ? xb[(size_t)(t + 2) * D + i] : 0.f)) / d1;
        float s2 = ((t - 1 >= 0) ? xb[(size_t)(t - 1) * D + i] : 0.f)
                 + ((t + 3 < S) ? xb[(size_t)(t + 3) * D + i] : 0.f);
        int d2i = ((t - 1 >= 0) ? 1 : 0) + ((t + 3 < S) ? 1 : 0);
        float v2 = d2i ? s2 / (float)d2i : 0.f;
        float wsum = 0.f;
        for (int s = t - 1; s <= t + 3; ++s)
            if (s >= 0 && s < S) wsum += xb[(size_t)s * D + i];
        int d3i = ((t - 1 > 0) ? (t - 1) : 0) + ((S - 4 - t > 0) ? (S - 4 - t) : 0);
        float v3 = d3i ? (total[b * D + i] - wsum) / (float)d3i : 0.f;
        z0[i] = comp[0] * v0 + comp[2] * v1 + comp[4] * v2 + comp[6] * v3;
        z1[i] = comp[1] * v0 + comp[3] * v1 + comp[5] * v2 + comp[7] * v3;
        xr[i] = x_t;
        __syncthreads();
        int o = tid;
        float acc = 0.f;
        #pragma unroll 8
        for (int k = 0; k < D; ++k) {
            acc += z0[k] * basis[k * D + o] + z1[k] * basis[DSQ + k * D + o]
                 + xr[k] * root[k * D + o];
        }
        out[(((size_t)b * S + t) << 8) + o] = acc + bias[o];
    }
}

// ---------------- K3: MFMA bulk GEMM --------------------------------------
// Block = 64(m) x 128(n), 128 thr = 2 waves (each 64x64 via 4x4 of 16x16x32).
// x tile staged once (swizzled); B triple-buffered with prefetch distance 2,
// raw s_barrier + manual s_waitcnt vmcnt(8) — no full drain per step.
__global__ __launch_bounds__(128, 1) void k_bulk_mfma(
        const unsigned short* __restrict__ xh,   // padded rows: [1 + B*S + pad]
        const unsigned short* __restrict__ Cbs,  // [40][256][32]
        const float* __restrict__ Tb,
        float* __restrict__ out) {
    __shared__ __align__(16) unsigned short xs[68 * 256];     // 34816 B
    __shared__ __align__(16) unsigned short Bs[3][128 * 32];  // 3 x 8192 B
    const int tid  = threadIdx.x;
    const int lane = tid & 63;
    const int w    = tid >> 6;
    const int mblk = blockIdx.x;        // 0..255
    const int nblk = blockIdx.y;        // 0..1
    const int b  = mblk >> 5;
    const int t0 = (mblk & 31) << 6;
    const size_t rowbase = (size_t)b * S + t0;

    // stage x tile: 68 rows x 512B, chunk-swizzle LDS[r][c16] <- global (c16&24)|((c16^r)&7)
    #pragma unroll
    for (int q = 0; q < 17; ++q) {
        int F = (q * 128 + tid) * 16;
        int r = F >> 9;
        int c16 = (F >> 4) & 31;
        int gc = (c16 & 24) | ((c16 ^ r) & 7);
        gl2lds16((const char*)xh + ((rowbase + r) << 9) + (gc << 4), (char*)xs + F);
    }
    // stage B steps 0 and 1
    #pragma unroll
    for (int st = 0; st < 2; ++st) {
        const size_t gb = ((size_t)st * 256 + nblk * 128) << 6;
        #pragma unroll
        for (int q = 0; q < 4; ++q) {
            int i = q * 128 + tid;
            int rn = i >> 2, c = i & 3;
            int gc = c ^ (rn & 3) ^ ((rn >> 2) & 3);
            gl2lds16((const char*)Cbs + gb + ((size_t)rn << 6) + (gc << 4),
                     (char*)Bs[st] + i * 16);
        }
    }
    WAIT_VM4();     // x + B0 resident (B1 may be in flight)
    BARRIER();

    f32x4 acc[4][4] = {};
    const int rlo = lane & 15, q4 = lane >> 4;

    for (int step = 0; step < 40; ++step) {
        int cur = step % 3;
        int pf = (step + 2 < 40) ? step + 2 : 39;   // clamp: keep 4 issues/step
        int pbuf = (step + 2) % 3;
        {   // prefetch B for step+2
            const size_t gb = ((size_t)pf * 256 + nblk * 128) << 6;
            #pragma unroll
            for (int q = 0; q < 4; ++q) {
                int i = q * 128 + tid;
                int rn = i >> 2, c = i & 3;
                int gc = c ^ (rn & 3) ^ ((rn >> 2) & 3);
                gl2lds16((const char*)Cbs + gb + ((size_t)rn << 6) + (gc << 4),
                         (char*)Bs[pbuf] + i * 16);
            }
        }
        WAIT_VM8();   // all but newest 8 loads done => step's B resident

        int ji = step >> 3, kc = step & 7;
        bf16x8 a[4], bb[4];
        #pragma unroll
        for (int mt = 0; mt < 4; ++mt) {
            int r = mt * 16 + rlo + ji;          // 0..67
            int cc = kc * 4 + q4;
            int c16 = (cc & 24) | ((cc ^ r) & 7);
            a[mt] = *(const bf16x8*)((const char*)xs + (r << 9) + (c16 << 4));
        }
        #pragma unroll
        for (int nt = 0; nt < 4; ++nt) {
            int n = w * 64 + nt * 16 + rlo;
            int c = q4 ^ (n & 3) ^ ((n >> 2) & 3);
            bb[nt] = *(const bf16x8*)((const char*)Bs[cur] + (n << 6) + (c << 4));
        }
        #pragma unroll
        for (int mt = 0; mt < 4; ++mt)
            #pragma unroll
            for (int nt = 0; nt < 4; ++nt)
                acc[mt][nt] = __builtin_amdgcn_mfma_f32_16x16x32_bf16(a[mt], bb[nt], acc[mt][nt], 0, 0, 0);

        BARRIER();    // plain s_barrier: bounds wave skew; no vmcnt drain
    }

    // epilogue: C/D layout col=lane&15, row=(lane>>4)*4+i
    const int col = lane & 15, rq = (lane >> 4) << 2;
    #pragma unroll
    for (int nt = 0; nt < 4; ++nt) {
        int n = nblk * 128 + w * 64 + nt * 16 + col;
        float tb = Tb[b * D + n];
        #pragma unroll
        for (int mt = 0; mt < 4; ++mt) {
            #pragma unroll
            for (int i = 0; i < 4; ++i) {
                int t = t0 + mt * 16 + rq + i;
                if (t >= 1 && t <= S - 4)
                    out[(((size_t)b * S + t) << 8) + n] = acc[mt][nt][i] + tb;
            }
        }
    }
}

// ---------------- launch ----------------

extern "C" void kernel_launch(void* const* d_in, const int* in_sizes, int n_in,
                              void* d_out, int out_size, void* d_ws, size_t ws_size,
                              hipStream_t stream) {
    const float* x     = (const float*)d_in[0];
    const float* comp  = (const float*)d_in[1];
    const float* basis = (const float*)d_in[2];
    const float* root  = (const float*)d_in[3];
    const float* bias  = (const float*)d_in[4];
    float* out = (float*)d_out;

    char* ws = (char*)d_ws;
    float* total        = (float*)(ws);                    // 8192 B
    float* Tb           = (float*)(ws + 8192);             // 8192 B
    unsigned short* Cbs = (unsigned short*)(ws + 16384);   // 655360 B
    unsigned short* xh  = (unsigned short*)(ws + 671744);  // 16392 rows * 512 B

    hipMemsetAsync(ws, 0, 16384, stream);                  // zero total + Tb
    k_prep     <<<dim3(B, 64), 256, 0, stream>>>(x, xh, total);
    k_weights  <<<224,         256, 0, stream>>>(basis, comp, root, bias, total, x, Cbs, Tb, out);
    k_bulk_mfma<<<dim3(256, 2), 128, 0, stream>>>(xh, Cbs, Tb, out);
}

// Round 4
// 121.966 us; speedup vs baseline: 2.9210x; 1.0466x over previous
//
#include <hip/hip_runtime.h>

#define D 256
#define S 2048
#define B 8
#define DSQ (D * D)   // 65536
#define INV3 (1.0f / 2043.0f)   // 1/(S-5)

typedef __bf16 bf16x8 __attribute__((ext_vector_type(8)));
typedef float f32x4 __attribute__((ext_vector_type(4)));

__device__ __forceinline__ unsigned short f2bf(float f) {
    union { float f; unsigned int u; } v; v.f = f;
    unsigned int u = v.u;
    u += 0x7fffu + ((u >> 16) & 1u);   // RTNE
    return (unsigned short)(u >> 16);
}

__device__ __forceinline__ void gl2lds16(const void* g, void* l) {
    __builtin_amdgcn_global_load_lds(
        (const __attribute__((address_space(1))) void*)g,
        (__attribute__((address_space(3))) void*)l, 16, 0, 0);
}

// ---------------- K1: bf16 cast + per-(b,chunk) channel partial sums -------
// grid (B, 64) x 256 thr; block = 32 rows; no atomics, no memset needed.
__global__ __launch_bounds__(256) void k_prep(const float* __restrict__ x,
                                              unsigned short* __restrict__ xh,
                                              float* __restrict__ part) {
    int b = blockIdx.x, chunk = blockIdx.y;
    int tid = threadIdx.x;
    int rg = tid >> 6;               // 0..3 row-group
    int c4 = (tid & 63) << 2;        // channel*4
    __shared__ float ps[4][D];
    int row0 = chunk * 32 + rg * 8;
    const float4* xb = (const float4*)(x + ((size_t)b * S + row0) * D + c4);
    ushort4* dst = (ushort4*)(xh + ((size_t)(1 + b * S + row0)) * D + c4);
    float4 s = {0.f, 0.f, 0.f, 0.f};
    #pragma unroll
    for (int i = 0; i < 8; ++i) {
        float4 v = xb[(size_t)i * 64];
        ushort4 o;
        o.x = f2bf(v.x); o.y = f2bf(v.y); o.z = f2bf(v.z); o.w = f2bf(v.w);
        dst[(size_t)i * 64] = o;
        s.x += v.x; s.y += v.y; s.z += v.z; s.w += v.w;
    }
    *(float4*)&ps[rg][c4] = s;
    __syncthreads();
    part[((size_t)(b * 64 + chunk)) * D + tid] =
        ps[0][tid] + ps[1][tid] + ps[2][tid] + ps[3][tid];
}

// ---------------- K2: Cbs build + Tb + boundary rows (one dispatch) --------
// blocks [0,160): Cbs; [160,168): Tb (one block per b); [168,200): boundary.
__global__ __launch_bounds__(256) void k_weights(
        const float* __restrict__ basis, const float* __restrict__ comp,
        const float* __restrict__ root, const float* __restrict__ bias,
        const float* __restrict__ part, const float* __restrict__ x,
        unsigned short* __restrict__ Cbs, float* __restrict__ Tb,
        float* __restrict__ out) {
    int blk = blockIdx.x;
    int tid = threadIdx.x;

    if (blk < 160) {                         // ---- Cbs[step][n][32] bf16
        int step = blk >> 2, q = blk & 3;    // q: quarter of the 32-k chunk
        int ji = step >> 3, kc = step & 7;
        int n = tid;
        float a0 = (ji == 2) ? 1.f : 0.f;
        float a1 = (ji == 1 || ji == 3) ? 0.5f : 0.f;
        float a2 = (ji == 0 || ji == 4) ? 0.5f : 0.f;
        float ar = (ji == 1) ? 1.f : 0.f;
        float cb0 = a0 * comp[0] + a1 * comp[2] + a2 * comp[4] - INV3 * comp[6];
        float cb1 = a0 * comp[1] + a1 * comp[3] + a2 * comp[5] - INV3 * comp[7];
        unsigned short buf[8];
        #pragma unroll
        for (int kk = 0; kk < 8; ++kk) {
            int i = kc * 32 + q * 8 + kk;
            float v = cb0 * basis[i * D + n] + cb1 * basis[DSQ + i * D + n]
                    + ar * root[i * D + n];
            buf[kk] = f2bf(v);
        }
        *(uint4*)(Cbs + ((size_t)step * 256 + n) * 32 + q * 8) = *(uint4*)buf;
    } else if (blk < 168) {                  // ---- Tb[b][o], single writer
        int b = blk - 160;
        __shared__ float tot[D];
        float t = 0.f;
        #pragma unroll 8
        for (int c = 0; c < 64; ++c) t += part[((size_t)(b * 64 + c)) * D + tid];
        tot[tid] = t;
        __syncthreads();
        int o = tid;
        float c30 = comp[6], c31 = comp[7];
        float acc = 0.f;
        #pragma unroll 4
        for (int k = 0; k < D; ++k)
            acc += tot[k] * (c30 * basis[k * D + o] + c31 * basis[DSQ + k * D + o]);
        Tb[b * D + o] = bias[o] + acc * INV3;
    } else {                                 // ---- boundary rows t in {0,S-3,S-2,S-1}
        int r = blk - 168;
        const int tl[4] = {0, S - 3, S - 2, S - 1};
        int t = tl[r & 3], b = r >> 2;
        __shared__ float z0[D], z1[D], xr[D];
        const float* xb = x + (size_t)b * S * D;
        int i = tid;
        float tot = 0.f;
        #pragma unroll 8
        for (int c = 0; c < 64; ++c) tot += part[((size_t)(b * 64 + c)) * D + i];
        float x_t = xb[(size_t)t * D + i];
        float v0 = (t + 1 < S) ? xb[(size_t)(t + 1) * D + i] : 0.f;
        float d1 = 1.f + ((t + 2 < S) ? 1.f : 0.f);
        float v1 = (x_t + ((t + 2 < S) ? xb[(size_t)(t + 2) * D + i] : 0.f)) / d1;
        float s2 = ((t - 1 >= 0) ? xb[(size_t)(t - 1) * D + i] : 0.f)
                 + ((t + 3 < S) ? xb[(size_t)(t + 3) * D + i] : 0.f);
        int d2i = ((t - 1 >= 0) ? 1 : 0) + ((t + 3 < S) ? 1 : 0);
        float v2 = d2i ? s2 / (float)d2i : 0.f;
        float wsum = 0.f;
        for (int s = t - 1; s <= t + 3; ++s)
            if (s >= 0 && s < S) wsum += xb[(size_t)s * D + i];
        int d3i = ((t - 1 > 0) ? (t - 1) : 0) + ((S - 4 - t > 0) ? (S - 4 - t) : 0);
        float v3 = d3i ? (tot - wsum) / (float)d3i : 0.f;
        z0[i] = comp[0] * v0 + comp[2] * v1 + comp[4] * v2 + comp[6] * v3;
        z1[i] = comp[1] * v0 + comp[3] * v1 + comp[5] * v2 + comp[7] * v3;
        xr[i] = x_t;
        __syncthreads();
        int o = tid;
        float acc = 0.f;
        #pragma unroll 8
        for (int k = 0; k < D; ++k) {
            acc += z0[k] * basis[k * D + o] + z1[k] * basis[DSQ + k * D + o]
                 + xr[k] * root[k * D + o];
        }
        out[(((size_t)b * S + t) << 8) + o] = acc + bias[o];
    }
}

// ---------------- K3: MFMA bulk GEMM — barrier-free K-loop -----------------
// Block = 128(m) x 64(n), 128 thr = 2 waves m-split (each 64m x 64n).
// A: x-tile (132 rows) staged once into LDS via global_load_lds, swizzled.
// B: global->VGPR fragments (1KB contiguous per load), register prefetch
//    distance 2, fully unrolled 40-step loop. NO barriers in the loop.
__global__ __launch_bounds__(128) void k_bulk_mfma(
        const unsigned short* __restrict__ xh,   // padded rows: [1 + B*S + 3]
        const unsigned short* __restrict__ Cbs,  // [40][256][32]
        const float* __restrict__ Tb,
        float* __restrict__ out) {
    __shared__ __align__(16) unsigned short xs[132 * 256];    // 67584 B
    const int tid  = threadIdx.x;
    const int lane = tid & 63;
    const int w    = tid >> 6;          // wave id -> m offset w*64
    const int mblk = blockIdx.x;        // 0..127
    const int nblk = blockIdx.y;        // 0..3
    const int b  = mblk >> 4;
    const int t0 = (mblk & 15) << 7;
    const size_t rowbase = (size_t)b * S + t0;   // padded row of x[b][t0-1]

    // stage x tile: 132 rows x 512B, chunk-swizzle LDS[r][c16] <- global (c16&24)|((c16^r)&7)
    #pragma unroll
    for (int q = 0; q < 33; ++q) {
        int F = (q * 128 + tid) * 16;
        int r = F >> 9;
        int c16 = (F >> 4) & 31;
        int gc = (c16 & 24) | ((c16 ^ r) & 7);
        gl2lds16((const char*)xh + ((rowbase + r) << 9) + (gc << 4), (char*)xs + F);
    }
    __syncthreads();   // one-time drain; K-loop below is barrier-free

    const int rlo = lane & 15, q4 = lane >> 4;
    // B fragment pointer for (step, nt): contiguous 1KB per wave-instruction
    #define BFRAG(st, nt) (*(const bf16x8*)(Cbs + \
        (((size_t)(st) * 256 + nblk * 64 + (nt) * 16 + rlo) << 5) + (q4 << 3)))

    f32x4 acc[4][4] = {};
    bf16x8 bb[3][4];
    #pragma unroll
    for (int nt = 0; nt < 4; ++nt) { bb[0][nt] = BFRAG(0, nt); bb[1][nt] = BFRAG(1, nt); }

    #pragma unroll
    for (int step = 0; step < 40; ++step) {
        const int cur = step % 3;
        const int pfs = (step + 2 < 40) ? step + 2 : 39;
        const int pbuf = (step + 2) % 3;
        #pragma unroll
        for (int nt = 0; nt < 4; ++nt) bb[pbuf][nt] = BFRAG(pfs, nt);

        const int ji = step >> 3, kc = step & 7;
        bf16x8 a[4];
        #pragma unroll
        for (int mt = 0; mt < 4; ++mt) {
            int r = w * 64 + mt * 16 + rlo + ji;       // 0..131
            int cc = kc * 4 + q4;
            int c16 = (cc & 24) | ((cc ^ r) & 7);
            a[mt] = *(const bf16x8*)((const char*)xs + (r << 9) + (c16 << 4));
        }
        #pragma unroll
        for (int mt = 0; mt < 4; ++mt)
            #pragma unroll
            for (int nt = 0; nt < 4; ++nt)
                acc[mt][nt] = __builtin_amdgcn_mfma_f32_16x16x32_bf16(a[mt], bb[cur][nt], acc[mt][nt], 0, 0, 0);
    }
    #undef BFRAG

    // epilogue: C/D layout col=lane&15, row=(lane>>4)*4+i
    const int col = lane & 15, rq = (lane >> 4) << 2;
    #pragma unroll
    for (int nt = 0; nt < 4; ++nt) {
        int n = nblk * 64 + nt * 16 + col;
        float tb = Tb[b * D + n];
        #pragma unroll
        for (int mt = 0; mt < 4; ++mt) {
            #pragma unroll
            for (int i = 0; i < 4; ++i) {
                int t = t0 + w * 64 + mt * 16 + rq + i;
                if (t >= 1 && t <= S - 4)
                    out[(((size_t)b * S + t) << 8) + n] = acc[mt][nt][i] + tb;
            }
        }
    }
}

// ---------------- launch ----------------

extern "C" void kernel_launch(void* const* d_in, const int* in_sizes, int n_in,
                              void* d_out, int out_size, void* d_ws, size_t ws_size,
                              hipStream_t stream) {
    const float* x     = (const float*)d_in[0];
    const float* comp  = (const float*)d_in[1];
    const float* basis = (const float*)d_in[2];
    const float* root  = (const float*)d_in[3];
    const float* bias  = (const float*)d_in[4];
    float* out = (float*)d_out;

    char* ws = (char*)d_ws;
    float* part         = (float*)(ws);                     // 512 KB
    float* Tb           = (float*)(ws + 524288);            // 8 KB
    unsigned short* Cbs = (unsigned short*)(ws + 532480);   // 640 KB
    unsigned short* xh  = (unsigned short*)(ws + 1187840);  // 16388 rows * 512 B

    k_prep     <<<dim3(B, 64), 256, 0, stream>>>(x, xh, part);
    k_weights  <<<200,         256, 0, stream>>>(basis, comp, root, bias, part, x, Cbs, Tb, out);
    k_bulk_mfma<<<dim3(128, 4), 128, 0, stream>>>(xh, Cbs, Tb, out);
}